// Round 10
// baseline (1697.878 us; speedup 1.0000x reference)
//
#include <hip/hip_runtime.h>
#include <hip/hip_bf16.h>

#define BB 64
#define TT 100
#define KSEL 2048
#define EMBD 300
#define EMBP 320
#define NSYN 16

typedef __attribute__((ext_vector_type(8))) _Float16 f16x8;
typedef __attribute__((ext_vector_type(4))) _Float16 f16x4;
typedef __attribute__((ext_vector_type(4))) float f32x4;

__device__ __forceinline__ float sigf(float x) { return 1.f / (1.f + __expf(-x)); }
__device__ __forceinline__ float tanhfast(float x) {
    float e = __expf(-2.f * fabsf(x));
    float r = (1.f - e) / (1.f + e);
    return copysignf(r, x);
}

// Stage raw f32 W_hh (row-permuted pr(n') = (n'&3)*512 + (n'>>2)) -> swizzled fp16 LDS.
// Once per block; 128 rows x 512 k.
__device__ __forceinline__ void stage_whh(const float* __restrict__ wraw, int nb, int tid,
                                          uint4* __restrict__ wlds) {
    for (int i = 0; i < 16; i++) {
        int idx = i * 512 + tid;
        int cc = idx >> 6, gi = idx & 63;
        int np = nb + cc;
        int pr = (np & 3) * 512 + (np >> 2);
        const float* s = wraw + (size_t)pr * 512 + gi * 8;
        float4 a = *(const float4*)s;
        float4 b = *(const float4*)(s + 4);
        f16x8 v;
        v[0] = (_Float16)a.x; v[1] = (_Float16)a.y; v[2] = (_Float16)a.z; v[3] = (_Float16)a.w;
        v[4] = (_Float16)b.x; v[5] = (_Float16)b.y; v[6] = (_Float16)b.z; v[7] = (_Float16)b.w;
        wlds[(cc << 6) | (gi ^ (cc & 7))] = __builtin_bit_cast(uint4, v);
    }
}

// ---------------- W_ih L1 -> fp16 permuted [n'][1024] ----------------
__global__ void wih_prep_kernel(const float* __restrict__ Wf, const float* __restrict__ Wb,
                                _Float16* __restrict__ Of, _Float16* __restrict__ Ob) {
    int dir = blockIdx.y;
    const float* W = dir ? Wb : Wf;
    _Float16* O = dir ? Ob : Of;
    int total = 2048 * 1024;
    for (int idx = blockIdx.x * 256 + threadIdx.x; idx < total; idx += gridDim.x * 256) {
        int np = idx >> 10, k = idx & 1023;
        int pr = (np & 3) * 512 + (np >> 2);
        O[idx] = (_Float16)W[(size_t)pr * 1024 + k];
    }
}

// ---------------- layer-0 input projection: embed fused, f32 W, fp16 gates out ----------
// Output gatesT[t][n'][b] fp16. blockIdx: x = t, y = n-tile(128), z = dir.
__global__ void __launch_bounds__(256)
xproj0_kernel(const int* __restrict__ X, const float* __restrict__ emb,
              const float* __restrict__ Wf, const float* __restrict__ Wb,
              const float* __restrict__ bihf, const float* __restrict__ bhhf,
              const float* __restrict__ bihb, const float* __restrict__ bhhb,
              _Float16* __restrict__ gTf, _Float16* __restrict__ gTb) {
    __shared__ _Float16 A_lds[64][40];
    __shared__ _Float16 B_lds[128][40];
    __shared__ float biasl[128];
    __shared__ int rid[64];
    int tid = threadIdx.x;
    int t = blockIdx.x;
    int n0 = blockIdx.y * 128;
    int dir = blockIdx.z;
    const float* W = dir ? Wb : Wf;
    const float* bih = dir ? bihb : bihf;
    const float* bhh = dir ? bhhb : bhhf;
    _Float16* gT = dir ? gTb : gTf;
    if (tid < 128) {
        int n = n0 + tid;
        int pr = (n & 3) * 512 + (n >> 2);
        biasl[tid] = bih[pr] + bhh[pr];
    }
    if (tid < 64) rid[tid] = X[tid * TT + t];
    int w = tid >> 6, l = tid & 63;
    int ml = tid >> 2, kk0 = (tid & 3) * 8;
    f32x4 acc[2][4] = {};
    __syncthreads();
    for (int k0 = 0; k0 < EMBP; k0 += 32) {
        {
            const float* arow = emb + (size_t)rid[ml] * EMBD;
#pragma unroll
            for (int c = 0; c < 8; c++) {
                int k = k0 + kk0 + c;
                A_lds[ml][kk0 + c] = (k < EMBD) ? (_Float16)arow[k] : (_Float16)0.f;
            }
        }
#pragma unroll
        for (int h = 0; h < 2; h++) {
            int idx = h * 256 + tid;
            int nl = idx >> 2, kb = (idx & 3) * 8;
            int n = n0 + nl;
            int pr = (n & 3) * 512 + (n >> 2);
            const float* brow = W + (size_t)pr * EMBD;
#pragma unroll
            for (int c = 0; c < 8; c++) {
                int k = k0 + kb + c;
                B_lds[nl][kb + c] = (k < EMBD) ? (_Float16)brow[k] : (_Float16)0.f;
            }
        }
        __syncthreads();
#pragma unroll
        for (int nt = 0; nt < 2; nt++) {
            f16x8 bfrag = *(const f16x8*)&B_lds[nt * 64 + w * 16 + (l & 15)][(l >> 4) * 8];
#pragma unroll
            for (int mb = 0; mb < 4; mb++) {
                f16x8 afrag = *(const f16x8*)&A_lds[mb * 16 + (l & 15)][(l >> 4) * 8];
                acc[nt][mb] = __builtin_amdgcn_mfma_f32_16x16x32_f16(afrag, bfrag, acc[nt][mb], 0, 0, 0);
            }
        }
        __syncthreads();
    }
#pragma unroll
    for (int nt = 0; nt < 2; nt++) {
        int n_local = nt * 64 + w * 16 + (l & 15);
        float bias = biasl[n_local];
#pragma unroll
        for (int mb = 0; mb < 4; mb++) {
            f16x4 st;
            st[0] = (_Float16)(acc[nt][mb][0] + bias);
            st[1] = (_Float16)(acc[nt][mb][1] + bias);
            st[2] = (_Float16)(acc[nt][mb][2] + bias);
            st[3] = (_Float16)(acc[nt][mb][3] + bias);
            *(f16x4*)&gT[((size_t)t * 2048 + n0 + n_local) * 64 + mb * 16 + (l >> 4) * 4] = st;
        }
    }
}

// ---------------- fused: lstm layer-0 (blocks 0-127) + xproj-L1 workers (128-255) ------
// lstm0: R9-proven protocol; exchange to per-t array exA[t][dir][64 b][512 j], tag = 1
// (each word written exactly once -> no ring reuse hazard). Workers consume exA with
// per-word tag checks (R6 protocol), middle-out t order matching readiness max(t,99-t).
__global__ void __launch_bounds__(512, 1)
fused0_kernel(const _Float16* __restrict__ gTf, const _Float16* __restrict__ gTb,
              const float* __restrict__ whhf, const float* __restrict__ whhb,
              const int* __restrict__ lengths, unsigned* __restrict__ exA,
              const _Float16* __restrict__ wi1f, const _Float16* __restrict__ wi1b,
              const float* __restrict__ bih1f, const float* __restrict__ bhh1f,
              const float* __restrict__ bih1b, const float* __restrict__ bhh1b,
              _Float16* __restrict__ g1f, _Float16* __restrict__ g1b) {
    extern __shared__ char smem[];
    int bid = blockIdx.x;
    int tid = threadIdx.x;
    if (bid < 128) {
        // ================= lstm layer 0 =================
        uint4* wlds = (uint4*)smem;                       // 131072 B
        uint4* hlds = (uint4*)(smem + 131072);            // 16384 B
        _Float16* hpack = (_Float16*)(smem + 147456);     // 1024 B
        int g = bid & 7, mem = bid >> 3;
        int dir = g & 1, bg = g >> 1;
        const _Float16* gT = dir ? gTb : gTf;
        const float* wraw = dir ? whhb : whhf;
        int w = tid >> 6, l = tid & 63;
        int lc = l & 15, hi = l >> 4;
        int q = lc & 3;
        int nb = mem * 128;
        int c = w * 16 + lc;
        stage_whh(wraw, nb, tid, wlds);
        float cst[4] = {};
        float hst[4] = {};
        int lenv[4];
#pragma unroll
        for (int r = 0; r < 4; r++) lenv[r] = lengths[bg * 16 + hi * 4 + r];
        __syncthreads();
        for (int s = 0; s < TT; s++) {
            int t = dir ? (TT - 1 - s) : s;
            f32x4 acc, acc2;
            {
                f16x4 gv = *(const f16x4*)(gT + ((size_t)t * 2048 + nb + c) * 64 + bg * 16 + hi * 4);
                acc[0] = (float)gv[0]; acc[1] = (float)gv[1];
                acc[2] = (float)gv[2]; acc[3] = (float)gv[3];
                acc2[0] = 0.f; acc2[1] = 0.f; acc2[2] = 0.f; acc2[3] = 0.f;
            }
            if (s > 0) {
                int tp = dir ? (t + 1) : (t - 1);
                const unsigned* exrow = exA + ((size_t)(tp * 2 + dir) * 64 + bg * 16) * 512;
                int sentinel = tid & 15;
                while (true) {
                    unsigned v = __hip_atomic_load(exrow + sentinel * 512 + tid, __ATOMIC_RELAXED,
                                                   __HIP_MEMORY_SCOPE_SYSTEM);
                    if ((v & 0xFFFFu) == 1u) break;
                    __builtin_amdgcn_s_sleep(2);
                }
                unsigned vals[16];
                while (true) {
                    bool ok = true;
#pragma unroll
                    for (int i = 0; i < 16; i++)
                        vals[i] = __hip_atomic_load(exrow + i * 512 + tid, __ATOMIC_RELAXED,
                                                    __HIP_MEMORY_SCOPE_SYSTEM);
#pragma unroll
                    for (int i = 0; i < 16; i++) ok &= ((vals[i] & 0xFFFFu) == 1u);
                    if (ok) break;
                }
                {
                    _Float16* hf = (_Float16*)hlds;
                    int gi = tid >> 3, el = tid & 7;
#pragma unroll
                    for (int i = 0; i < 16; i++) {
                        unsigned short hb = (unsigned short)(vals[i] >> 16);
                        hf[(((i << 6) | (gi ^ (i & 7))) << 3) + el] = __builtin_bit_cast(_Float16, hb);
                    }
                }
                __syncthreads();
#pragma unroll
                for (int ks = 0; ks < 16; ks += 2) {
                    int gg0 = ks * 4 + hi;
                    int gg1 = (ks + 1) * 4 + hi;
                    f16x8 af0 = *(const f16x8*)((const char*)hlds + (((lc << 6) | (gg0 ^ (lc & 7))) << 4));
                    f16x8 bf0 = *(const f16x8*)((const char*)wlds + (((c << 6) | (gg0 ^ (lc & 7))) << 4));
                    f16x8 af1 = *(const f16x8*)((const char*)hlds + (((lc << 6) | (gg1 ^ (lc & 7))) << 4));
                    f16x8 bf1 = *(const f16x8*)((const char*)wlds + (((c << 6) | (gg1 ^ (lc & 7))) << 4));
                    acc = __builtin_amdgcn_mfma_f32_16x16x32_f16(af0, bf0, acc, 0, 0, 0);
                    acc2 = __builtin_amdgcn_mfma_f32_16x16x32_f16(af1, bf1, acc2, 0, 0, 0);
                }
                acc[0] += acc2[0]; acc[1] += acc2[1]; acc[2] += acc2[2]; acc[3] += acc2[3];
                __syncthreads();
            }
#pragma unroll
            for (int r = 0; r < 4; r++) {
                float pre = acc[r];
                float sg = sigf(pre), th = tanhfast(pre);
                float a = (q == 2) ? th : sg;
                float p1 = __shfl_xor(a, 1);
                float p2 = __shfl_xor(a, 2);
                float p3 = __shfl_xor(p1, 2);
                float gi_ = q == 0 ? a : q == 1 ? p1 : q == 2 ? p2 : p3;
                float gf_ = q == 0 ? p1 : q == 1 ? a : q == 2 ? p3 : p2;
                float gg_ = q == 0 ? p2 : q == 1 ? p3 : q == 2 ? a : p1;
                float go_ = q == 0 ? p3 : q == 1 ? p2 : q == 2 ? p1 : a;
                float cn = gf_ * cst[r] + gi_ * gg_;
                float hn = go_ * tanhfast(cn);
                if (t < lenv[r]) { cst[r] = cn; hst[r] = hn; }
                if (q == 0) hpack[(hi * 4 + r) * 32 + w * 4 + (lc >> 2)] = (_Float16)hst[r];
            }
            __syncthreads();
            {
                int bb = tid >> 5, jl = tid & 31;
                _Float16 hv = hpack[bb * 32 + jl];
                unsigned wv = ((unsigned)__builtin_bit_cast(unsigned short, hv) << 16) | 1u;
                __hip_atomic_store(exA + ((size_t)(t * 2 + dir) * 64 + bg * 16 + bb) * 512 + mem * 32 + jl,
                                   wv, __ATOMIC_RELAXED, __HIP_MEMORY_SCOPE_SYSTEM);
            }
            // no trailing barrier: next step's staging-sync drains these stores
        }
    } else {
        // ================= xproj-L1 worker =================
        _Float16(*A_lds)[40] = (_Float16(*)[40])smem;                 // 5120 B
        _Float16(*B_lds)[40] = (_Float16(*)[40])(smem + 5120);        // 20480 B ([256][40])
        float* biasl = (float*)(smem + 5120 + 20480);                 // 1024 B
        int wb = bid - 128;
        int half = tid >> 8, tl = tid & 255;
        int w = tl >> 6, l = tl & 63;
        for (int job = wb; job < 1600; job += 128) {
            int trank = job >> 4, inner = job & 15;
            int t = (trank & 1) ? (49 - (trank >> 1)) : (50 + (trank >> 1));
            int d = inner & 1, nq = inner >> 1;
            const _Float16* Wi = d ? wi1b : wi1f;
            const float* bih = d ? bih1b : bih1f;
            const float* bhh = d ? bhh1b : bhh1f;
            _Float16* gT = d ? g1b : g1f;
            int n0 = nq * 256;
            if (tl < 128) {
                int n = n0 + half * 128 + tl;
                int pr = (n & 3) * 512 + (n >> 2);
                biasl[half * 128 + tl] = bih[pr] + bhh[pr];
            }
            f32x4 acc[2][4] = {};
            __syncthreads();
            for (int kc = 0; kc < 32; kc++) {
                int dcur = kc >> 4;
                int kk = (kc & 15) * 32;
                {
                    int row = tid >> 3, c0 = (tid & 7) * 4;
                    const unsigned* src = exA + ((size_t)(t * 2 + dcur) * 64 + row) * 512 + kk + c0;
                    unsigned v0, v1, v2, v3;
                    while (true) {
                        v0 = __hip_atomic_load(src + 0, __ATOMIC_RELAXED, __HIP_MEMORY_SCOPE_SYSTEM);
                        v1 = __hip_atomic_load(src + 1, __ATOMIC_RELAXED, __HIP_MEMORY_SCOPE_SYSTEM);
                        v2 = __hip_atomic_load(src + 2, __ATOMIC_RELAXED, __HIP_MEMORY_SCOPE_SYSTEM);
                        v3 = __hip_atomic_load(src + 3, __ATOMIC_RELAXED, __HIP_MEMORY_SCOPE_SYSTEM);
                        bool ok = ((v0 & 0xFFFFu) == 1u) & ((v1 & 0xFFFFu) == 1u) &
                                  ((v2 & 0xFFFFu) == 1u) & ((v3 & 0xFFFFu) == 1u);
                        if (ok) break;
                        __builtin_amdgcn_s_sleep(4);
                    }
                    A_lds[row][c0 + 0] = __builtin_bit_cast(_Float16, (unsigned short)(v0 >> 16));
                    A_lds[row][c0 + 1] = __builtin_bit_cast(_Float16, (unsigned short)(v1 >> 16));
                    A_lds[row][c0 + 2] = __builtin_bit_cast(_Float16, (unsigned short)(v2 >> 16));
                    A_lds[row][c0 + 3] = __builtin_bit_cast(_Float16, (unsigned short)(v3 >> 16));
                }
#pragma unroll
                for (int u = 0; u < 2; u++) {
                    int e = tl * 2 + u;
                    int nl = e >> 2, kb = (e & 3) * 8;
                    *(uint4*)&B_lds[half * 128 + nl][kb] =
                        *(const uint4*)(Wi + (size_t)(n0 + half * 128 + nl) * 1024 + kc * 32 + kb);
                }
                __syncthreads();
#pragma unroll
                for (int nt = 0; nt < 2; nt++) {
                    f16x8 bfrag = *(const f16x8*)&B_lds[half * 128 + nt * 64 + w * 16 + (l & 15)][(l >> 4) * 8];
#pragma unroll
                    for (int mb = 0; mb < 4; mb++) {
                        f16x8 afrag = *(const f16x8*)&A_lds[mb * 16 + (l & 15)][(l >> 4) * 8];
                        acc[nt][mb] = __builtin_amdgcn_mfma_f32_16x16x32_f16(afrag, bfrag, acc[nt][mb], 0, 0, 0);
                    }
                }
                __syncthreads();
            }
#pragma unroll
            for (int nt = 0; nt < 2; nt++) {
                int n_local = half * 128 + nt * 64 + w * 16 + (l & 15);
                float bias = biasl[n_local];
#pragma unroll
                for (int mb = 0; mb < 4; mb++) {
                    f16x4 st;
                    st[0] = (_Float16)(acc[nt][mb][0] + bias);
                    st[1] = (_Float16)(acc[nt][mb][1] + bias);
                    st[2] = (_Float16)(acc[nt][mb][2] + bias);
                    st[3] = (_Float16)(acc[nt][mb][3] + bias);
                    *(f16x4*)&gT[((size_t)t * 2048 + n0 + n_local) * 64 + mb * 16 + (l >> 4) * 4] = st;
                }
            }
            __syncthreads();
        }
    }
}

// ---------------- lstm layer 1: R9-proven ring protocol (raw f32 W staging) ------------
__global__ void __launch_bounds__(512, 1)
lstm_ring_kernel(const _Float16* __restrict__ gTf, const _Float16* __restrict__ gTb,
                 const float* __restrict__ whhf, const float* __restrict__ whhb,
                 const int* __restrict__ lengths, _Float16* __restrict__ hs,
                 unsigned* __restrict__ ex) {
    extern __shared__ char smem[];
    uint4* wlds = (uint4*)smem;
    uint4* hlds = (uint4*)(smem + 131072);
    _Float16* hpack = (_Float16*)(smem + 147456);
    int bid = blockIdx.x;
    int g = bid & 7, mem = bid >> 3;
    int dir = g & 1, bg = g >> 1;
    const _Float16* gT = dir ? gTb : gTf;
    const float* wraw = dir ? whhb : whhf;
    int tid = threadIdx.x;
    int w = tid >> 6, l = tid & 63;
    int lc = l & 15, hi = l >> 4;
    int q = lc & 3;
    int nb = mem * 128;
    int c = w * 16 + lc;
    stage_whh(wraw, nb, tid, wlds);
    float cst[4] = {};
    float hst[4] = {};
    int lenv[4];
#pragma unroll
    for (int r = 0; r < 4; r++) lenv[r] = lengths[bg * 16 + hi * 4 + r];
    __syncthreads();

    for (int s = 0; s < TT; s++) {
        int t = dir ? (TT - 1 - s) : s;
        f32x4 acc, acc2;
        {
            f16x4 gv = *(const f16x4*)(gT + ((size_t)t * 2048 + nb + c) * 64 + bg * 16 + hi * 4);
            acc[0] = (float)gv[0]; acc[1] = (float)gv[1];
            acc[2] = (float)gv[2]; acc[3] = (float)gv[3];
            acc2[0] = 0.f; acc2[1] = 0.f; acc2[2] = 0.f; acc2[3] = 0.f;
        }
        if (s > 0) {
            const unsigned* exrow = ex + ((size_t)(((s - 1) & 1) * 8 + g) * 16) * 512;
            unsigned want = (unsigned)s;
            unsigned vals[16];
            int sentinel = tid & 15;
            while (true) {
                unsigned v = __hip_atomic_load(exrow + sentinel * 512 + tid, __ATOMIC_RELAXED,
                                               __HIP_MEMORY_SCOPE_SYSTEM);
                if ((v & 0xFFFFu) == want) break;
                __builtin_amdgcn_s_sleep(2);
            }
            while (true) {
                bool ok = true;
#pragma unroll
                for (int i = 0; i < 16; i++)
                    vals[i] = __hip_atomic_load(exrow + i * 512 + tid, __ATOMIC_RELAXED,
                                                __HIP_MEMORY_SCOPE_SYSTEM);
#pragma unroll
                for (int i = 0; i < 16; i++) ok &= ((vals[i] & 0xFFFFu) == want);
                if (ok) break;
            }
            {
                _Float16* hf = (_Float16*)hlds;
                int gi = tid >> 3, el = tid & 7;
#pragma unroll
                for (int i = 0; i < 16; i++) {
                    unsigned short hb = (unsigned short)(vals[i] >> 16);
                    hf[(((i << 6) | (gi ^ (i & 7))) << 3) + el] = __builtin_bit_cast(_Float16, hb);
                }
            }
            __syncthreads();
#pragma unroll
            for (int ks = 0; ks < 16; ks += 2) {
                int gg0 = ks * 4 + hi;
                int gg1 = (ks + 1) * 4 + hi;
                f16x8 af0 = *(const f16x8*)((const char*)hlds + (((lc << 6) | (gg0 ^ (lc & 7))) << 4));
                f16x8 bf0 = *(const f16x8*)((const char*)wlds + (((c << 6) | (gg0 ^ (lc & 7))) << 4));
                f16x8 af1 = *(const f16x8*)((const char*)hlds + (((lc << 6) | (gg1 ^ (lc & 7))) << 4));
                f16x8 bf1 = *(const f16x8*)((const char*)wlds + (((c << 6) | (gg1 ^ (lc & 7))) << 4));
                acc = __builtin_amdgcn_mfma_f32_16x16x32_f16(af0, bf0, acc, 0, 0, 0);
                acc2 = __builtin_amdgcn_mfma_f32_16x16x32_f16(af1, bf1, acc2, 0, 0, 0);
            }
            acc[0] += acc2[0]; acc[1] += acc2[1]; acc[2] += acc2[2]; acc[3] += acc2[3];
            __syncthreads();
        }
#pragma unroll
        for (int r = 0; r < 4; r++) {
            float pre = acc[r];
            float sg = sigf(pre), th = tanhfast(pre);
            float a = (q == 2) ? th : sg;
            float p1 = __shfl_xor(a, 1);
            float p2 = __shfl_xor(a, 2);
            float p3 = __shfl_xor(p1, 2);
            float gi_ = q == 0 ? a : q == 1 ? p1 : q == 2 ? p2 : p3;
            float gf_ = q == 0 ? p1 : q == 1 ? a : q == 2 ? p3 : p2;
            float gg_ = q == 0 ? p2 : q == 1 ? p3 : q == 2 ? a : p1;
            float go_ = q == 0 ? p3 : q == 1 ? p2 : q == 2 ? p1 : a;
            float cn = gf_ * cst[r] + gi_ * gg_;
            float hn = go_ * tanhfast(cn);
            if (t < lenv[r]) { cst[r] = cn; hst[r] = hn; }
            if (q == 0) hpack[(hi * 4 + r) * 32 + w * 4 + (lc >> 2)] = (_Float16)hst[r];
        }
        __syncthreads();
        {
            int bb = tid >> 5, jl = tid & 31;
            _Float16 hv = hpack[bb * 32 + jl];
            unsigned wv = ((unsigned)__builtin_bit_cast(unsigned short, hv) << 16)
                        | (unsigned)(s + 1);
            __hip_atomic_store(ex + (((size_t)(s & 1) * 8 + g) * 16 + bb) * 512 + mem * 32 + jl,
                               wv, __ATOMIC_RELAXED, __HIP_MEMORY_SCOPE_SYSTEM);
            hs[((size_t)(t * 64 + bg * 16 + bb)) * 1024 + dir * 512 + mem * 32 + jl] = hv;
        }
        // trailing barrier removed: next step's staging-sync drains these stores
    }
}

// ---------------- ctx = xsel @ out_W^T + out_b ----------------
__global__ void ctx_kernel(const _Float16* __restrict__ hs1, const float* __restrict__ outW,
                           const float* __restrict__ outb, const int* __restrict__ sel_b,
                           const int* __restrict__ sel_t, float* __restrict__ out) {
    __shared__ float As[16][68];
    __shared__ float Bs[16][68];
    __shared__ int rowbase[64];
    int tid = threadIdx.x;
    int m0 = blockIdx.x * 64, n0 = blockIdx.y * 64;
    if (tid < 64) {
        int m = m0 + tid;
        rowbase[tid] = (sel_t[m] * 64 + sel_b[m]) * 1024;
    }
    __syncthreads();
    int tx = tid & 15, ty = tid >> 4;
    float acc[4][4] = {};
    for (int k0 = 0; k0 < 1024; k0 += 16) {
        for (int e = tid; e < 1024; e += 256) {
            int ml = e >> 4, k = e & 15;
            As[k][ml] = (float)hs1[(size_t)rowbase[ml] + k0 + k];
        }
        for (int e = tid; e < 1024; e += 256) {
            int nl = e >> 4, k = e & 15;
            int n = n0 + nl;
            Bs[k][nl] = (n < EMBD) ? outW[(size_t)n * 1024 + k0 + k] : 0.f;
        }
        __syncthreads();
#pragma unroll
        for (int kk = 0; kk < 16; kk++) {
            float4 a4 = *(const float4*)&As[kk][ty * 4];
            float4 b4 = *(const float4*)&Bs[kk][tx * 4];
            float av[4] = {a4.x, a4.y, a4.z, a4.w};
            float bv[4] = {b4.x, b4.y, b4.z, b4.w};
#pragma unroll
            for (int i = 0; i < 4; i++)
#pragma unroll
                for (int jj = 0; jj < 4; jj++) acc[i][jj] += av[i] * bv[jj];
        }
        __syncthreads();
    }
    for (int i = 0; i < 4; i++) {
        int m = m0 + ty * 4 + i;
        for (int jj = 0; jj < 4; jj++) {
            int n = n0 + tx * 4 + jj;
            if (n < EMBD) out[(size_t)m * EMBD + n] = acc[i][jj] + outb[n];
        }
    }
}

// ---------------- cls = einsum('ksd,kd->ks', exp_W[eidx], xsel) + exp_b[eidx] ----------------
__global__ void cls_kernel(const _Float16* __restrict__ hs1, const float* __restrict__ expW,
                           const float* __restrict__ expb, const int* __restrict__ sel_b,
                           const int* __restrict__ sel_t, const int* __restrict__ eidx,
                           float* __restrict__ out) {
    __shared__ float xr[1024];
    int r = blockIdx.x;
    int tid = threadIdx.x;
    int e = eidx[r];
    int base = (sel_t[r] * 64 + sel_b[r]) * 1024;
    for (int qq = tid; qq < 1024; qq += 256) xr[qq] = (float)hs1[(size_t)base + qq];
    __syncthreads();
    int lane = tid & 63, wid = tid >> 6;
    for (int p = 0; p < 4; p++) {
        int s = p * 4 + wid;
        const float* wrow = expW + ((size_t)e * NSYN + s) * 1024;
        float partial = 0.f;
#pragma unroll
        for (int i = 0; i < 16; i++) {
            int k = lane + 64 * i;
            partial += xr[k] * wrow[k];
        }
        for (int off = 32; off; off >>= 1) partial += __shfl_down(partial, off);
        if (lane == 0) out[(size_t)KSEL * EMBD + (size_t)r * NSYN + s] = partial + expb[e * NSYN + s];
    }
}

extern "C" void kernel_launch(void* const* d_in, const int* in_sizes, int n_in,
                              void* d_out, int out_size, void* d_ws, size_t ws_size,
                              hipStream_t stream) {
    const int* X = (const int*)d_in[0];
    const int* Xlen = (const int*)d_in[1];
    const int* sel_b = (const int*)d_in[2];
    const int* sel_t = (const int*)d_in[3];
    const int* eidx = (const int*)d_in[4];
    const float* emb = (const float*)d_in[5];
    const float* w_ih_l0f = (const float*)d_in[6];
    const float* w_hh_l0f = (const float*)d_in[7];
    const float* b_ih_l0f = (const float*)d_in[8];
    const float* b_hh_l0f = (const float*)d_in[9];
    const float* w_ih_l0b = (const float*)d_in[10];
    const float* w_hh_l0b = (const float*)d_in[11];
    const float* b_ih_l0b = (const float*)d_in[12];
    const float* b_hh_l0b = (const float*)d_in[13];
    const float* w_ih_l1f = (const float*)d_in[14];
    const float* w_hh_l1f = (const float*)d_in[15];
    const float* b_ih_l1f = (const float*)d_in[16];
    const float* b_hh_l1f = (const float*)d_in[17];
    const float* w_ih_l1b = (const float*)d_in[18];
    const float* w_hh_l1b = (const float*)d_in[19];
    const float* b_ih_l1b = (const float*)d_in[20];
    const float* b_hh_l1b = (const float*)d_in[21];
    const float* outW = (const float*)d_in[22];
    const float* outb = (const float*)d_in[23];
    const float* expW = (const float*)d_in[24];
    const float* expb = (const float*)d_in[25];

    char* ws = (char*)d_ws;
    _Float16* g0f = (_Float16*)ws;                            // 26,214,400 B [t][n'][b] fp16
    _Float16* g0b = (_Float16*)(ws + 26214400);               // 26,214,400 B
    _Float16* g1f = (_Float16*)(ws + 52428800);               // 26,214,400 B
    _Float16* g1b = (_Float16*)(ws + 78643200);               // 26,214,400 B
    _Float16* hs1 = (_Float16*)(ws + 104857600);              // 13,107,200 B [(t*64+b)][1024]
    unsigned* exA = (unsigned*)(ws + 117964800);              // 26,214,400 B [t][dir][64][512]
    unsigned* ring = (unsigned*)(ws + 144179200);             //    524,288 B (layer-1 2-slot ring)
    _Float16* wi1f = (_Float16*)(ws + 144703488);             //  4,194,304 B [2048][1024]
    _Float16* wi1b = (_Float16*)(ws + 148897792);             //  4,194,304 B
    size_t needed = 153092096;
    if (ws_size < needed) return;  // diagnostic: absmax would equal max|ref|
    float* out = (float*)d_out;

    hipFuncSetAttribute((const void*)fused0_kernel,
                        hipFuncAttributeMaxDynamicSharedMemorySize, 148480);
    hipFuncSetAttribute((const void*)lstm_ring_kernel,
                        hipFuncAttributeMaxDynamicSharedMemorySize, 148480);

    hipMemsetAsync(exA, 0, 26214400, stream);   // clear layer-0 tags (replay-safe)
    hipMemsetAsync(ring, 0, 524288, stream);    // clear layer-1 ring tags

    wih_prep_kernel<<<dim3(1024, 2), 256, 0, stream>>>(w_ih_l1f, w_ih_l1b, wi1f, wi1b);

    xproj0_kernel<<<dim3(100, 16, 2), 256, 0, stream>>>(X, emb, w_ih_l0f, w_ih_l0b,
        b_ih_l0f, b_hh_l0f, b_ih_l0b, b_hh_l0b, g0f, g0b);

    {
        const _Float16* a0 = g0f; const _Float16* a1 = g0b;
        const float* a2 = w_hh_l0f; const float* a3 = w_hh_l0b;
        const int* a4 = Xlen; unsigned* a5 = exA;
        const _Float16* a6 = wi1f; const _Float16* a7 = wi1b;
        const float* a8 = b_ih_l1f; const float* a9 = b_hh_l1f;
        const float* a10 = b_ih_l1b; const float* a11 = b_hh_l1b;
        _Float16* a12 = g1f; _Float16* a13 = g1b;
        void* args[] = {(void*)&a0, (void*)&a1, (void*)&a2, (void*)&a3, (void*)&a4,
                        (void*)&a5, (void*)&a6, (void*)&a7, (void*)&a8, (void*)&a9,
                        (void*)&a10, (void*)&a11, (void*)&a12, (void*)&a13};
        hipLaunchCooperativeKernel((const void*)fused0_kernel, dim3(256), dim3(512), args, 148480, stream);
    }

    {
        const _Float16* a0 = g1f; const _Float16* a1 = g1b;
        const float* a2 = w_hh_l1f; const float* a3 = w_hh_l1b;
        const int* a4 = Xlen; _Float16* a5 = hs1; unsigned* a6 = ring;
        void* args[] = {(void*)&a0, (void*)&a1, (void*)&a2, (void*)&a3,
                        (void*)&a4, (void*)&a5, (void*)&a6};
        hipLaunchCooperativeKernel((const void*)lstm_ring_kernel, dim3(128), dim3(512), args, 148480, stream);
    }

    ctx_kernel<<<dim3(32, 5), 256, 0, stream>>>(hs1, outW, outb, sel_b, sel_t, out);
    cls_kernel<<<KSEL, 256, 0, stream>>>(hs1, expW, expb, sel_b, sel_t, eidx, out);
}

// Round 11
// 1414.265 us; speedup vs baseline: 1.2005x; 1.2005x over previous
//
#include <hip/hip_runtime.h>
#include <hip/hip_bf16.h>

#define BB 64
#define TT 100
#define KSEL 2048
#define EMBD 300
#define EMBP 320
#define NSYN 16

typedef __attribute__((ext_vector_type(8))) _Float16 f16x8;
typedef __attribute__((ext_vector_type(4))) _Float16 f16x4;
typedef __attribute__((ext_vector_type(4))) float f32x4;

__device__ __forceinline__ float sigf(float x) { return 1.f / (1.f + __expf(-x)); }
__device__ __forceinline__ float tanhfast(float x) {
    float e = __expf(-2.f * fabsf(x));
    float r = (1.f - e) / (1.f + e);
    return copysignf(r, x);
}

// Stage raw f32 W_hh (row-permuted pr(n') = (n'&3)*512 + (n'>>2)) -> swizzled fp16 LDS.
// Once per block; 128 rows x 512 k. [proven R10]
__device__ __forceinline__ void stage_whh(const float* __restrict__ wraw, int nb, int tid,
                                          uint4* __restrict__ wlds) {
    for (int i = 0; i < 16; i++) {
        int idx = i * 512 + tid;
        int cc = idx >> 6, gi = idx & 63;
        int np = nb + cc;
        int pr = (np & 3) * 512 + (np >> 2);
        const float* s = wraw + (size_t)pr * 512 + gi * 8;
        float4 a = *(const float4*)s;
        float4 b = *(const float4*)(s + 4);
        f16x8 v;
        v[0] = (_Float16)a.x; v[1] = (_Float16)a.y; v[2] = (_Float16)a.z; v[3] = (_Float16)a.w;
        v[4] = (_Float16)b.x; v[5] = (_Float16)b.y; v[6] = (_Float16)b.z; v[7] = (_Float16)b.w;
        wlds[(cc << 6) | (gi ^ (cc & 7))] = __builtin_bit_cast(uint4, v);
    }
}

// ---------------- layer-0 input projection: embed fused, f32 W, fp16 gates out [proven R10] ----
// Output gatesT[t][n'][b] fp16. blockIdx: x = t, y = n-tile(128), z = dir.
__global__ void __launch_bounds__(256)
xproj0_kernel(const int* __restrict__ X, const float* __restrict__ emb,
              const float* __restrict__ Wf, const float* __restrict__ Wb,
              const float* __restrict__ bihf, const float* __restrict__ bhhf,
              const float* __restrict__ bihb, const float* __restrict__ bhhb,
              _Float16* __restrict__ gTf, _Float16* __restrict__ gTb) {
    __shared__ _Float16 A_lds[64][40];
    __shared__ _Float16 B_lds[128][40];
    __shared__ float biasl[128];
    __shared__ int rid[64];
    int tid = threadIdx.x;
    int t = blockIdx.x;
    int n0 = blockIdx.y * 128;
    int dir = blockIdx.z;
    const float* W = dir ? Wb : Wf;
    const float* bih = dir ? bihb : bihf;
    const float* bhh = dir ? bhhb : bhhf;
    _Float16* gT = dir ? gTb : gTf;
    if (tid < 128) {
        int n = n0 + tid;
        int pr = (n & 3) * 512 + (n >> 2);
        biasl[tid] = bih[pr] + bhh[pr];
    }
    if (tid < 64) rid[tid] = X[tid * TT + t];
    int w = tid >> 6, l = tid & 63;
    int ml = tid >> 2, kk0 = (tid & 3) * 8;
    f32x4 acc[2][4] = {};
    __syncthreads();
    for (int k0 = 0; k0 < EMBP; k0 += 32) {
        {
            const float* arow = emb + (size_t)rid[ml] * EMBD;
#pragma unroll
            for (int c = 0; c < 8; c++) {
                int k = k0 + kk0 + c;
                A_lds[ml][kk0 + c] = (k < EMBD) ? (_Float16)arow[k] : (_Float16)0.f;
            }
        }
#pragma unroll
        for (int h = 0; h < 2; h++) {
            int idx = h * 256 + tid;
            int nl = idx >> 2, kb = (idx & 3) * 8;
            int n = n0 + nl;
            int pr = (n & 3) * 512 + (n >> 2);
            const float* brow = W + (size_t)pr * EMBD;
#pragma unroll
            for (int c = 0; c < 8; c++) {
                int k = k0 + kb + c;
                B_lds[nl][kb + c] = (k < EMBD) ? (_Float16)brow[k] : (_Float16)0.f;
            }
        }
        __syncthreads();
#pragma unroll
        for (int nt = 0; nt < 2; nt++) {
            f16x8 bfrag = *(const f16x8*)&B_lds[nt * 64 + w * 16 + (l & 15)][(l >> 4) * 8];
#pragma unroll
            for (int mb = 0; mb < 4; mb++) {
                f16x8 afrag = *(const f16x8*)&A_lds[mb * 16 + (l & 15)][(l >> 4) * 8];
                acc[nt][mb] = __builtin_amdgcn_mfma_f32_16x16x32_f16(afrag, bfrag, acc[nt][mb], 0, 0, 0);
            }
        }
        __syncthreads();
    }
#pragma unroll
    for (int nt = 0; nt < 2; nt++) {
        int n_local = nt * 64 + w * 16 + (l & 15);
        float bias = biasl[n_local];
#pragma unroll
        for (int mb = 0; mb < 4; mb++) {
            f16x4 st;
            st[0] = (_Float16)(acc[nt][mb][0] + bias);
            st[1] = (_Float16)(acc[nt][mb][1] + bias);
            st[2] = (_Float16)(acc[nt][mb][2] + bias);
            st[3] = (_Float16)(acc[nt][mb][3] + bias);
            *(f16x4*)&gT[((size_t)t * 2048 + n0 + n_local) * 64 + mb * 16 + (l >> 4) * 4] = st;
        }
    }
}

// ---------------- layer-1 input projection: A = hs0 fp16, B from f32 W (on-the-fly cvt) ----
__global__ void __launch_bounds__(256)
xproj1_kernel(const _Float16* __restrict__ A,
              const float* __restrict__ Wf, const float* __restrict__ Wb,
              const float* __restrict__ bihf, const float* __restrict__ bhhf,
              const float* __restrict__ bihb, const float* __restrict__ bhhb,
              _Float16* __restrict__ gTf, _Float16* __restrict__ gTb) {
    __shared__ _Float16 A_lds[64][40];
    __shared__ _Float16 B_lds[128][40];
    __shared__ float biasl[128];
    int tid = threadIdx.x;
    int t = blockIdx.x;
    int n0 = blockIdx.y * 128;
    int dir = blockIdx.z;
    const float* W = dir ? Wb : Wf;
    const float* bih = dir ? bihb : bihf;
    const float* bhh = dir ? bhhb : bhhf;
    _Float16* gT = dir ? gTb : gTf;
    if (tid < 128) {
        int n = n0 + tid;
        int pr = (n & 3) * 512 + (n >> 2);
        biasl[tid] = bih[pr] + bhh[pr];
    }
    int w = tid >> 6, l = tid & 63;
    int ml = tid >> 2, kk0 = (tid & 3) * 8;
    f32x4 acc[2][4] = {};
    __syncthreads();
    for (int k0 = 0; k0 < 1024; k0 += 32) {
        *(uint4*)&A_lds[ml][kk0] = *(const uint4*)(A + (size_t)(t * 64 + ml) * 1024 + k0 + kk0);
#pragma unroll
        for (int h = 0; h < 2; h++) {
            int idx = h * 256 + tid;
            int nl = idx >> 2, kb = (idx & 3) * 8;
            int n = n0 + nl;
            int pr = (n & 3) * 512 + (n >> 2);
            const float* src = W + (size_t)pr * 1024 + k0 + kb;
            float4 v0 = *(const float4*)(src);
            float4 v1 = *(const float4*)(src + 4);
            B_lds[nl][kb + 0] = (_Float16)v0.x; B_lds[nl][kb + 1] = (_Float16)v0.y;
            B_lds[nl][kb + 2] = (_Float16)v0.z; B_lds[nl][kb + 3] = (_Float16)v0.w;
            B_lds[nl][kb + 4] = (_Float16)v1.x; B_lds[nl][kb + 5] = (_Float16)v1.y;
            B_lds[nl][kb + 6] = (_Float16)v1.z; B_lds[nl][kb + 7] = (_Float16)v1.w;
        }
        __syncthreads();
#pragma unroll
        for (int nt = 0; nt < 2; nt++) {
            f16x8 bfrag = *(const f16x8*)&B_lds[nt * 64 + w * 16 + (l & 15)][(l >> 4) * 8];
#pragma unroll
            for (int mb = 0; mb < 4; mb++) {
                f16x8 afrag = *(const f16x8*)&A_lds[mb * 16 + (l & 15)][(l >> 4) * 8];
                acc[nt][mb] = __builtin_amdgcn_mfma_f32_16x16x32_f16(afrag, bfrag, acc[nt][mb], 0, 0, 0);
            }
        }
        __syncthreads();
    }
#pragma unroll
    for (int nt = 0; nt < 2; nt++) {
        int n_local = nt * 64 + w * 16 + (l & 15);
        float bias = biasl[n_local];
#pragma unroll
        for (int mb = 0; mb < 4; mb++) {
            f16x4 st;
            st[0] = (_Float16)(acc[nt][mb][0] + bias);
            st[1] = (_Float16)(acc[nt][mb][1] + bias);
            st[2] = (_Float16)(acc[nt][mb][2] + bias);
            st[3] = (_Float16)(acc[nt][mb][3] + bias);
            *(f16x4*)&gT[((size_t)t * 2048 + n0 + n_local) * 64 + mb * 16 + (l >> 4) * 4] = st;
        }
    }
}

// ---------------- bilstm layer: R9-proven ring protocol; stage_whh; no trailing barrier ----
// 128 wgs x 512 thr (cooperative). g = bid&7: dir = g&1, bg = g>>1. member = bid>>3 owns
// 128 n'-cols (W-slice 128KB in LDS). Exchange word u32 = (fp16 h)<<16 | tag, relaxed
// SYSTEM atomics, 2-slot ring ex[slot][g][16 b][512 j], tag = tagbase+s+1. No fences.
__global__ void __launch_bounds__(512, 1)
lstm_tag_kernel(const _Float16* __restrict__ gTf, const _Float16* __restrict__ gTb,
                const float* __restrict__ whhf, const float* __restrict__ whhb,
                const int* __restrict__ lengths, _Float16* __restrict__ hs,
                unsigned* __restrict__ ex, int tagbase) {
    extern __shared__ char smem[];
    uint4* wlds = (uint4*)smem;                       // 131072 B: [128 c][64 gi] swizzled
    uint4* hlds = (uint4*)(smem + 131072);            // 16384 B:  [16 b][64 gi] swizzled
    _Float16* hpack = (_Float16*)(smem + 147456);     // 1024 B:   [16 b][32 jl]
    int bid = blockIdx.x;
    int g = bid & 7, mem = bid >> 3;
    int dir = g & 1, bg = g >> 1;
    const _Float16* gT = dir ? gTb : gTf;
    const float* wraw = dir ? whhb : whhf;
    int tid = threadIdx.x;
    int w = tid >> 6, l = tid & 63;
    int lc = l & 15, hi = l >> 4;
    int q = lc & 3;
    int nb = mem * 128;
    int c = w * 16 + lc;
    stage_whh(wraw, nb, tid, wlds);
    float cst[4] = {};
    float hst[4] = {};
    int lenv[4];
#pragma unroll
    for (int r = 0; r < 4; r++) lenv[r] = lengths[bg * 16 + hi * 4 + r];
    __syncthreads();

    for (int s = 0; s < TT; s++) {
        int t = dir ? (TT - 1 - s) : s;
        f32x4 acc, acc2;
        {
            f16x4 gv = *(const f16x4*)(gT + ((size_t)t * 2048 + nb + c) * 64 + bg * 16 + hi * 4);
            acc[0] = (float)gv[0]; acc[1] = (float)gv[1];
            acc[2] = (float)gv[2]; acc[3] = (float)gv[3];
            acc2[0] = 0.f; acc2[1] = 0.f; acc2[2] = 0.f; acc2[3] = 0.f;
        }
        if (s > 0) {
            const unsigned* exrow = ex + ((size_t)(((s - 1) & 1) * 8 + g) * 16) * 512;
            unsigned want = (unsigned)(tagbase + s);
            unsigned vals[16];
            int sentinel = tid & 15;
            while (true) {
                unsigned v = __hip_atomic_load(exrow + sentinel * 512 + tid, __ATOMIC_RELAXED,
                                               __HIP_MEMORY_SCOPE_SYSTEM);
                if ((v & 0xFFFFu) == want) break;
                __builtin_amdgcn_s_sleep(2);
            }
            while (true) {
                bool ok = true;
#pragma unroll
                for (int i = 0; i < 16; i++)
                    vals[i] = __hip_atomic_load(exrow + i * 512 + tid, __ATOMIC_RELAXED,
                                                __HIP_MEMORY_SCOPE_SYSTEM);
#pragma unroll
                for (int i = 0; i < 16; i++) ok &= ((vals[i] & 0xFFFFu) == want);
                if (ok) break;
            }
            {
                _Float16* hf = (_Float16*)hlds;
                int gi = tid >> 3, el = tid & 7;
#pragma unroll
                for (int i = 0; i < 16; i++) {
                    unsigned short hb = (unsigned short)(vals[i] >> 16);
                    hf[(((i << 6) | (gi ^ (i & 7))) << 3) + el] = __builtin_bit_cast(_Float16, hb);
                }
            }
            __syncthreads();
#pragma unroll
            for (int ks = 0; ks < 16; ks += 2) {
                int gg0 = ks * 4 + hi;
                int gg1 = (ks + 1) * 4 + hi;
                f16x8 af0 = *(const f16x8*)((const char*)hlds + (((lc << 6) | (gg0 ^ (lc & 7))) << 4));
                f16x8 bf0 = *(const f16x8*)((const char*)wlds + (((c << 6) | (gg0 ^ (lc & 7))) << 4));
                f16x8 af1 = *(const f16x8*)((const char*)hlds + (((lc << 6) | (gg1 ^ (lc & 7))) << 4));
                f16x8 bf1 = *(const f16x8*)((const char*)wlds + (((c << 6) | (gg1 ^ (lc & 7))) << 4));
                acc = __builtin_amdgcn_mfma_f32_16x16x32_f16(af0, bf0, acc, 0, 0, 0);
                acc2 = __builtin_amdgcn_mfma_f32_16x16x32_f16(af1, bf1, acc2, 0, 0, 0);
            }
            acc[0] += acc2[0]; acc[1] += acc2[1]; acc[2] += acc2[2]; acc[3] += acc2[3];
            __syncthreads();
        }
#pragma unroll
        for (int r = 0; r < 4; r++) {
            float pre = acc[r];
            float sg = sigf(pre), th = tanhfast(pre);
            float a = (q == 2) ? th : sg;
            float p1 = __shfl_xor(a, 1);
            float p2 = __shfl_xor(a, 2);
            float p3 = __shfl_xor(p1, 2);
            float gi_ = q == 0 ? a : q == 1 ? p1 : q == 2 ? p2 : p3;
            float gf_ = q == 0 ? p1 : q == 1 ? a : q == 2 ? p3 : p2;
            float gg_ = q == 0 ? p2 : q == 1 ? p3 : q == 2 ? a : p1;
            float go_ = q == 0 ? p3 : q == 1 ? p2 : q == 2 ? p1 : a;
            float cn = gf_ * cst[r] + gi_ * gg_;
            float hn = go_ * tanhfast(cn);
            if (t < lenv[r]) { cst[r] = cn; hst[r] = hn; }
            if (q == 0) hpack[(hi * 4 + r) * 32 + w * 4 + (lc >> 2)] = (_Float16)hst[r];
        }
        __syncthreads();
        {
            int bb = tid >> 5, jl = tid & 31;
            _Float16 hv = hpack[bb * 32 + jl];
            unsigned wv = ((unsigned)__builtin_bit_cast(unsigned short, hv) << 16)
                        | (unsigned)(tagbase + s + 1);
            __hip_atomic_store(ex + (((size_t)(s & 1) * 8 + g) * 16 + bb) * 512 + mem * 32 + jl,
                               wv, __ATOMIC_RELAXED, __HIP_MEMORY_SCOPE_SYSTEM);
            hs[((size_t)(t * 64 + bg * 16 + bb)) * 1024 + dir * 512 + mem * 32 + jl] = hv;
        }
        // trailing barrier removed [proven R10]: next step's staging barriers order hpack reuse
    }
}

// ---------------- ctx = xsel @ out_W^T + out_b ----------------
__global__ void ctx_kernel(const _Float16* __restrict__ hs1, const float* __restrict__ outW,
                           const float* __restrict__ outb, const int* __restrict__ sel_b,
                           const int* __restrict__ sel_t, float* __restrict__ out) {
    __shared__ float As[16][68];
    __shared__ float Bs[16][68];
    __shared__ int rowbase[64];
    int tid = threadIdx.x;
    int m0 = blockIdx.x * 64, n0 = blockIdx.y * 64;
    if (tid < 64) {
        int m = m0 + tid;
        rowbase[tid] = (sel_t[m] * 64 + sel_b[m]) * 1024;
    }
    __syncthreads();
    int tx = tid & 15, ty = tid >> 4;
    float acc[4][4] = {};
    for (int k0 = 0; k0 < 1024; k0 += 16) {
        for (int e = tid; e < 1024; e += 256) {
            int ml = e >> 4, k = e & 15;
            As[k][ml] = (float)hs1[(size_t)rowbase[ml] + k0 + k];
        }
        for (int e = tid; e < 1024; e += 256) {
            int nl = e >> 4, k = e & 15;
            int n = n0 + nl;
            Bs[k][nl] = (n < EMBD) ? outW[(size_t)n * 1024 + k0 + k] : 0.f;
        }
        __syncthreads();
#pragma unroll
        for (int kk = 0; kk < 16; kk++) {
            float4 a4 = *(const float4*)&As[kk][ty * 4];
            float4 b4 = *(const float4*)&Bs[kk][tx * 4];
            float av[4] = {a4.x, a4.y, a4.z, a4.w};
            float bv[4] = {b4.x, b4.y, b4.z, b4.w};
#pragma unroll
            for (int i = 0; i < 4; i++)
#pragma unroll
                for (int jj = 0; jj < 4; jj++) acc[i][jj] += av[i] * bv[jj];
        }
        __syncthreads();
    }
    for (int i = 0; i < 4; i++) {
        int m = m0 + ty * 4 + i;
        for (int jj = 0; jj < 4; jj++) {
            int n = n0 + tx * 4 + jj;
            if (n < EMBD) out[(size_t)m * EMBD + n] = acc[i][jj] + outb[n];
        }
    }
}

// ---------------- cls = einsum('ksd,kd->ks', exp_W[eidx], xsel) + exp_b[eidx] ----------------
__global__ void cls_kernel(const _Float16* __restrict__ hs1, const float* __restrict__ expW,
                           const float* __restrict__ expb, const int* __restrict__ sel_b,
                           const int* __restrict__ sel_t, const int* __restrict__ eidx,
                           float* __restrict__ out) {
    __shared__ float xr[1024];
    int r = blockIdx.x;
    int tid = threadIdx.x;
    int e = eidx[r];
    int base = (sel_t[r] * 64 + sel_b[r]) * 1024;
    for (int qq = tid; qq < 1024; qq += 256) xr[qq] = (float)hs1[(size_t)base + qq];
    __syncthreads();
    int lane = tid & 63, wid = tid >> 6;
    for (int p = 0; p < 4; p++) {
        int s = p * 4 + wid;
        const float* wrow = expW + ((size_t)e * NSYN + s) * 1024;
        float partial = 0.f;
#pragma unroll
        for (int i = 0; i < 16; i++) {
            int k = lane + 64 * i;
            partial += xr[k] * wrow[k];
        }
        for (int off = 32; off; off >>= 1) partial += __shfl_down(partial, off);
        if (lane == 0) out[(size_t)KSEL * EMBD + (size_t)r * NSYN + s] = partial + expb[e * NSYN + s];
    }
}

extern "C" void kernel_launch(void* const* d_in, const int* in_sizes, int n_in,
                              void* d_out, int out_size, void* d_ws, size_t ws_size,
                              hipStream_t stream) {
    const int* X = (const int*)d_in[0];
    const int* Xlen = (const int*)d_in[1];
    const int* sel_b = (const int*)d_in[2];
    const int* sel_t = (const int*)d_in[3];
    const int* eidx = (const int*)d_in[4];
    const float* emb = (const float*)d_in[5];
    const float* w_ih_l0f = (const float*)d_in[6];
    const float* w_hh_l0f = (const float*)d_in[7];
    const float* b_ih_l0f = (const float*)d_in[8];
    const float* b_hh_l0f = (const float*)d_in[9];
    const float* w_ih_l0b = (const float*)d_in[10];
    const float* w_hh_l0b = (const float*)d_in[11];
    const float* b_ih_l0b = (const float*)d_in[12];
    const float* b_hh_l0b = (const float*)d_in[13];
    const float* w_ih_l1f = (const float*)d_in[14];
    const float* w_hh_l1f = (const float*)d_in[15];
    const float* b_ih_l1f = (const float*)d_in[16];
    const float* b_hh_l1f = (const float*)d_in[17];
    const float* w_ih_l1b = (const float*)d_in[18];
    const float* w_hh_l1b = (const float*)d_in[19];
    const float* b_ih_l1b = (const float*)d_in[20];
    const float* b_hh_l1b = (const float*)d_in[21];
    const float* outW = (const float*)d_in[22];
    const float* outb = (const float*)d_in[23];
    const float* expW = (const float*)d_in[24];
    const float* expb = (const float*)d_in[25];

    char* ws = (char*)d_ws;
    _Float16* gates_f = (_Float16*)ws;                        // 26,214,400 B [t][n'][b] fp16
    _Float16* gates_b = (_Float16*)(ws + 26214400);           // 26,214,400 B
    _Float16* hs0 = (_Float16*)(ws + 52428800);               // 13,107,200 B [(t*64+b)][1024]
    _Float16* hs1 = (_Float16*)(ws + 65536000);               // 13,107,200 B
    unsigned* ring = (unsigned*)(ws + 78643200);              //    524,288 B (2-slot tagged ring)
    size_t needed = 79167488;
    if (ws_size < needed) return;  // diagnostic: absmax would equal max|ref|
    float* out = (float*)d_out;

    hipFuncSetAttribute((const void*)lstm_tag_kernel,
                        hipFuncAttributeMaxDynamicSharedMemorySize, 148480);

    hipMemsetAsync(ring, 0, 524288, stream);   // clear ring tags (replay-safe)

    xproj0_kernel<<<dim3(100, 16, 2), 256, 0, stream>>>(X, emb, w_ih_l0f, w_ih_l0b,
        b_ih_l0f, b_hh_l0f, b_ih_l0b, b_hh_l0b, gates_f, gates_b);

    {
        const _Float16* a0 = gates_f; const _Float16* a1 = gates_b;
        const float* a2 = w_hh_l0f; const float* a3 = w_hh_l0b;
        const int* a4 = Xlen; _Float16* a5 = hs0; unsigned* a6 = ring; int a7 = 0;
        void* args[] = {(void*)&a0, (void*)&a1, (void*)&a2, (void*)&a3,
                        (void*)&a4, (void*)&a5, (void*)&a6, (void*)&a7};
        hipLaunchCooperativeKernel((const void*)lstm_tag_kernel, dim3(128), dim3(512), args, 148480, stream);
    }

    xproj1_kernel<<<dim3(100, 16, 2), 256, 0, stream>>>(hs0, w_ih_l1f, w_ih_l1b,
        b_ih_l1f, b_hh_l1f, b_ih_l1b, b_hh_l1b, gates_f, gates_b);

    {
        const _Float16* a0 = gates_f; const _Float16* a1 = gates_b;
        const float* a2 = w_hh_l1f; const float* a3 = w_hh_l1b;
        const int* a4 = Xlen; _Float16* a5 = hs1; unsigned* a6 = ring; int a7 = 128;
        void* args[] = {(void*)&a0, (void*)&a1, (void*)&a2, (void*)&a3,
                        (void*)&a4, (void*)&a5, (void*)&a6, (void*)&a7};
        hipLaunchCooperativeKernel((const void*)lstm_tag_kernel, dim3(128), dim3(512), args, 148480, stream);
    }

    ctx_kernel<<<dim3(32, 5), 256, 0, stream>>>(hs1, outW, outb, sel_b, sel_t, out);
    cls_kernel<<<KSEL, 256, 0, stream>>>(hs1, expW, expb, sel_b, sel_t, eidx, out);
}

// Round 12
// 1102.748 us; speedup vs baseline: 1.5397x; 1.2825x over previous
//
#include <hip/hip_runtime.h>
#include <hip/hip_bf16.h>

#define BB 64
#define TT 100
#define KSEL 2048
#define EMBD 300
#define EMBP 320
#define NSYN 16

typedef __attribute__((ext_vector_type(8))) _Float16 f16x8;
typedef __attribute__((ext_vector_type(4))) _Float16 f16x4;
typedef __attribute__((ext_vector_type(4))) float f32x4;

__device__ __forceinline__ float sigf(float x) { return 1.f / (1.f + __expf(-x)); }
__device__ __forceinline__ float tanhfast(float x) {
    float e = __expf(-2.f * fabsf(x));
    float r = (1.f - e) / (1.f + e);
    return copysignf(r, x);
}

// Stage raw f32 W_hh (row-permuted pr(n') = (n'&3)*512 + (n'>>2)) -> swizzled fp16 LDS.
__device__ __forceinline__ void stage_whh(const float* __restrict__ wraw, int nb, int tid,
                                          uint4* __restrict__ wlds) {
    for (int i = 0; i < 16; i++) {
        int idx = i * 512 + tid;
        int cc = idx >> 6, gi = idx & 63;
        int np = nb + cc;
        int pr = (np & 3) * 512 + (np >> 2);
        const float* s = wraw + (size_t)pr * 512 + gi * 8;
        float4 a = *(const float4*)s;
        float4 b = *(const float4*)(s + 4);
        f16x8 v;
        v[0] = (_Float16)a.x; v[1] = (_Float16)a.y; v[2] = (_Float16)a.z; v[3] = (_Float16)a.w;
        v[4] = (_Float16)b.x; v[5] = (_Float16)b.y; v[6] = (_Float16)b.z; v[7] = (_Float16)b.w;
        wlds[(cc << 6) | (gi ^ (cc & 7))] = __builtin_bit_cast(uint4, v);
    }
}

// f32 row chunk -> f16x8 with tail predication (rows are 16B-aligned; k multiple of 8)
__device__ __forceinline__ f16x8 load8_f32_cvt(const float* __restrict__ row, int k, int Kreal) {
    f16x8 v;
    if (k + 8 <= Kreal) {
        float4 a = *(const float4*)(row + k);
        float4 b = *(const float4*)(row + k + 4);
        v[0] = (_Float16)a.x; v[1] = (_Float16)a.y; v[2] = (_Float16)a.z; v[3] = (_Float16)a.w;
        v[4] = (_Float16)b.x; v[5] = (_Float16)b.y; v[6] = (_Float16)b.z; v[7] = (_Float16)b.w;
    } else {
#pragma unroll
        for (int c = 0; c < 8; c++)
            v[c] = (k + c < Kreal) ? (_Float16)row[k + c] : (_Float16)0.f;
    }
    return v;
}

// ---------------- layer-0 input projection: embed fused, VECTORIZED staging ----------
// Output gatesT[t][n'][b] fp16. blockIdx: x = t, y = n-tile(128), z = dir.
__global__ void __launch_bounds__(256)
xproj0_kernel(const int* __restrict__ X, const float* __restrict__ emb,
              const float* __restrict__ Wf, const float* __restrict__ Wb,
              const float* __restrict__ bihf, const float* __restrict__ bhhf,
              const float* __restrict__ bihb, const float* __restrict__ bhhb,
              _Float16* __restrict__ gTf, _Float16* __restrict__ gTb) {
    __shared__ _Float16 A_lds[64][40];
    __shared__ _Float16 B_lds[128][40];
    __shared__ float biasl[128];
    __shared__ int rid[64];
    int tid = threadIdx.x;
    int t = blockIdx.x;
    int n0 = blockIdx.y * 128;
    int dir = blockIdx.z;
    const float* W = dir ? Wb : Wf;
    const float* bih = dir ? bihb : bihf;
    const float* bhh = dir ? bhhb : bhhf;
    _Float16* gT = dir ? gTb : gTf;
    if (tid < 128) {
        int n = n0 + tid;
        int pr = (n & 3) * 512 + (n >> 2);
        biasl[tid] = bih[pr] + bhh[pr];
    }
    if (tid < 64) rid[tid] = X[tid * TT + t];
    int w = tid >> 6, l = tid & 63;
    int ml = tid >> 2, kk0 = (tid & 3) * 8;
    f32x4 acc[2][4] = {};
    __syncthreads();
    for (int k0 = 0; k0 < EMBP; k0 += 32) {
        {
            const float* arow = emb + (size_t)rid[ml] * EMBD;
            f16x8 v = load8_f32_cvt(arow, k0 + kk0, EMBD);
            *(uint4*)&A_lds[ml][kk0] = __builtin_bit_cast(uint4, v);
        }
#pragma unroll
        for (int h = 0; h < 2; h++) {
            int idx = h * 256 + tid;
            int nl = idx >> 2, kb = (idx & 3) * 8;
            int n = n0 + nl;
            int pr = (n & 3) * 512 + (n >> 2);
            const float* brow = W + (size_t)pr * EMBD;
            f16x8 v = load8_f32_cvt(brow, k0 + kb, EMBD);
            *(uint4*)&B_lds[nl][kb] = __builtin_bit_cast(uint4, v);
        }
        __syncthreads();
#pragma unroll
        for (int nt = 0; nt < 2; nt++) {
            f16x8 bfrag = *(const f16x8*)&B_lds[nt * 64 + w * 16 + (l & 15)][(l >> 4) * 8];
#pragma unroll
            for (int mb = 0; mb < 4; mb++) {
                f16x8 afrag = *(const f16x8*)&A_lds[mb * 16 + (l & 15)][(l >> 4) * 8];
                acc[nt][mb] = __builtin_amdgcn_mfma_f32_16x16x32_f16(afrag, bfrag, acc[nt][mb], 0, 0, 0);
            }
        }
        __syncthreads();
    }
#pragma unroll
    for (int nt = 0; nt < 2; nt++) {
        int n_local = nt * 64 + w * 16 + (l & 15);
        float bias = biasl[n_local];
#pragma unroll
        for (int mb = 0; mb < 4; mb++) {
            f16x4 st;
            st[0] = (_Float16)(acc[nt][mb][0] + bias);
            st[1] = (_Float16)(acc[nt][mb][1] + bias);
            st[2] = (_Float16)(acc[nt][mb][2] + bias);
            st[3] = (_Float16)(acc[nt][mb][3] + bias);
            *(f16x4*)&gT[((size_t)t * 2048 + n0 + n_local) * 64 + mb * 16 + (l >> 4) * 4] = st;
        }
    }
}

// ---------------- layer-1 input projection: A = hs0 fp16, B from f32 W (float4 cvt) ----
__global__ void __launch_bounds__(256)
xproj1_kernel(const _Float16* __restrict__ A,
              const float* __restrict__ Wf, const float* __restrict__ Wb,
              const float* __restrict__ bihf, const float* __restrict__ bhhf,
              const float* __restrict__ bihb, const float* __restrict__ bhhb,
              _Float16* __restrict__ gTf, _Float16* __restrict__ gTb) {
    __shared__ _Float16 A_lds[64][40];
    __shared__ _Float16 B_lds[128][40];
    __shared__ float biasl[128];
    int tid = threadIdx.x;
    int t = blockIdx.x;
    int n0 = blockIdx.y * 128;
    int dir = blockIdx.z;
    const float* W = dir ? Wb : Wf;
    const float* bih = dir ? bihb : bihf;
    const float* bhh = dir ? bhhb : bhhf;
    _Float16* gT = dir ? gTb : gTf;
    if (tid < 128) {
        int n = n0 + tid;
        int pr = (n & 3) * 512 + (n >> 2);
        biasl[tid] = bih[pr] + bhh[pr];
    }
    int w = tid >> 6, l = tid & 63;
    int ml = tid >> 2, kk0 = (tid & 3) * 8;
    f32x4 acc[2][4] = {};
    __syncthreads();
    for (int k0 = 0; k0 < 1024; k0 += 32) {
        *(uint4*)&A_lds[ml][kk0] = *(const uint4*)(A + (size_t)(t * 64 + ml) * 1024 + k0 + kk0);
#pragma unroll
        for (int h = 0; h < 2; h++) {
            int idx = h * 256 + tid;
            int nl = idx >> 2, kb = (idx & 3) * 8;
            int n = n0 + nl;
            int pr = (n & 3) * 512 + (n >> 2);
            const float* src = W + (size_t)pr * 1024 + k0 + kb;
            float4 v0 = *(const float4*)(src);
            float4 v1 = *(const float4*)(src + 4);
            f16x8 v;
            v[0] = (_Float16)v0.x; v[1] = (_Float16)v0.y; v[2] = (_Float16)v0.z; v[3] = (_Float16)v0.w;
            v[4] = (_Float16)v1.x; v[5] = (_Float16)v1.y; v[6] = (_Float16)v1.z; v[7] = (_Float16)v1.w;
            *(uint4*)&B_lds[nl][kb] = __builtin_bit_cast(uint4, v);
        }
        __syncthreads();
#pragma unroll
        for (int nt = 0; nt < 2; nt++) {
            f16x8 bfrag = *(const f16x8*)&B_lds[nt * 64 + w * 16 + (l & 15)][(l >> 4) * 8];
#pragma unroll
            for (int mb = 0; mb < 4; mb++) {
                f16x8 afrag = *(const f16x8*)&A_lds[mb * 16 + (l & 15)][(l >> 4) * 8];
                acc[nt][mb] = __builtin_amdgcn_mfma_f32_16x16x32_f16(afrag, bfrag, acc[nt][mb], 0, 0, 0);
            }
        }
        __syncthreads();
    }
#pragma unroll
    for (int nt = 0; nt < 2; nt++) {
        int n_local = nt * 64 + w * 16 + (l & 15);
        float bias = biasl[n_local];
#pragma unroll
        for (int mb = 0; mb < 4; mb++) {
            f16x4 st;
            st[0] = (_Float16)(acc[nt][mb][0] + bias);
            st[1] = (_Float16)(acc[nt][mb][1] + bias);
            st[2] = (_Float16)(acc[nt][mb][2] + bias);
            st[3] = (_Float16)(acc[nt][mb][3] + bias);
            *(f16x4*)&gT[((size_t)t * 2048 + n0 + n_local) * 64 + mb * 16 + (l >> 4) * 4] = st;
        }
    }
}

// ---------------- bilstm layer: R9-proven ring protocol; stage_whh; no trailing barrier ----
__global__ void __launch_bounds__(512, 1)
lstm_tag_kernel(const _Float16* __restrict__ gTf, const _Float16* __restrict__ gTb,
                const float* __restrict__ whhf, const float* __restrict__ whhb,
                const int* __restrict__ lengths, _Float16* __restrict__ hs,
                unsigned* __restrict__ ex, int tagbase) {
    extern __shared__ char smem[];
    uint4* wlds = (uint4*)smem;                       // 131072 B
    uint4* hlds = (uint4*)(smem + 131072);            // 16384 B
    _Float16* hpack = (_Float16*)(smem + 147456);     // 1024 B
    int bid = blockIdx.x;
    int g = bid & 7, mem = bid >> 3;
    int dir = g & 1, bg = g >> 1;
    const _Float16* gT = dir ? gTb : gTf;
    const float* wraw = dir ? whhb : whhf;
    int tid = threadIdx.x;
    int w = tid >> 6, l = tid & 63;
    int lc = l & 15, hi = l >> 4;
    int q = lc & 3;
    int nb = mem * 128;
    int c = w * 16 + lc;
    stage_whh(wraw, nb, tid, wlds);
    float cst[4] = {};
    float hst[4] = {};
    int lenv[4];
#pragma unroll
    for (int r = 0; r < 4; r++) lenv[r] = lengths[bg * 16 + hi * 4 + r];
    __syncthreads();

    for (int s = 0; s < TT; s++) {
        int t = dir ? (TT - 1 - s) : s;
        f32x4 acc, acc2;
        {
            f16x4 gv = *(const f16x4*)(gT + ((size_t)t * 2048 + nb + c) * 64 + bg * 16 + hi * 4);
            acc[0] = (float)gv[0]; acc[1] = (float)gv[1];
            acc[2] = (float)gv[2]; acc[3] = (float)gv[3];
            acc2[0] = 0.f; acc2[1] = 0.f; acc2[2] = 0.f; acc2[3] = 0.f;
        }
        if (s > 0) {
            const unsigned* exrow = ex + ((size_t)(((s - 1) & 1) * 8 + g) * 16) * 512;
            unsigned want = (unsigned)(tagbase + s);
            unsigned vals[16];
            int sentinel = tid & 15;
            while (true) {
                unsigned v = __hip_atomic_load(exrow + sentinel * 512 + tid, __ATOMIC_RELAXED,
                                               __HIP_MEMORY_SCOPE_SYSTEM);
                if ((v & 0xFFFFu) == want) break;
                __builtin_amdgcn_s_sleep(2);
            }
            while (true) {
                bool ok = true;
#pragma unroll
                for (int i = 0; i < 16; i++)
                    vals[i] = __hip_atomic_load(exrow + i * 512 + tid, __ATOMIC_RELAXED,
                                                __HIP_MEMORY_SCOPE_SYSTEM);
#pragma unroll
                for (int i = 0; i < 16; i++) ok &= ((vals[i] & 0xFFFFu) == want);
                if (ok) break;
            }
            {
                _Float16* hf = (_Float16*)hlds;
                int gi = tid >> 3, el = tid & 7;
#pragma unroll
                for (int i = 0; i < 16; i++) {
                    unsigned short hb = (unsigned short)(vals[i] >> 16);
                    hf[(((i << 6) | (gi ^ (i & 7))) << 3) + el] = __builtin_bit_cast(_Float16, hb);
                }
            }
            __syncthreads();
#pragma unroll
            for (int ks = 0; ks < 16; ks += 2) {
                int gg0 = ks * 4 + hi;
                int gg1 = (ks + 1) * 4 + hi;
                f16x8 af0 = *(const f16x8*)((const char*)hlds + (((lc << 6) | (gg0 ^ (lc & 7))) << 4));
                f16x8 bf0 = *(const f16x8*)((const char*)wlds + (((c << 6) | (gg0 ^ (lc & 7))) << 4));
                f16x8 af1 = *(const f16x8*)((const char*)hlds + (((lc << 6) | (gg1 ^ (lc & 7))) << 4));
                f16x8 bf1 = *(const f16x8*)((const char*)wlds + (((c << 6) | (gg1 ^ (lc & 7))) << 4));
                acc = __builtin_amdgcn_mfma_f32_16x16x32_f16(af0, bf0, acc, 0, 0, 0);
                acc2 = __builtin_amdgcn_mfma_f32_16x16x32_f16(af1, bf1, acc2, 0, 0, 0);
            }
            acc[0] += acc2[0]; acc[1] += acc2[1]; acc[2] += acc2[2]; acc[3] += acc2[3];
            __syncthreads();
        }
#pragma unroll
        for (int r = 0; r < 4; r++) {
            float pre = acc[r];
            float sg = sigf(pre), th = tanhfast(pre);
            float a = (q == 2) ? th : sg;
            float p1 = __shfl_xor(a, 1);
            float p2 = __shfl_xor(a, 2);
            float p3 = __shfl_xor(p1, 2);
            float gi_ = q == 0 ? a : q == 1 ? p1 : q == 2 ? p2 : p3;
            float gf_ = q == 0 ? p1 : q == 1 ? a : q == 2 ? p3 : p2;
            float gg_ = q == 0 ? p2 : q == 1 ? p3 : q == 2 ? a : p1;
            float go_ = q == 0 ? p3 : q == 1 ? p2 : q == 2 ? p1 : a;
            float cn = gf_ * cst[r] + gi_ * gg_;
            float hn = go_ * tanhfast(cn);
            if (t < lenv[r]) { cst[r] = cn; hst[r] = hn; }
            if (q == 0) hpack[(hi * 4 + r) * 32 + w * 4 + (lc >> 2)] = (_Float16)hst[r];
        }
        __syncthreads();
        {
            int bb = tid >> 5, jl = tid & 31;
            _Float16 hv = hpack[bb * 32 + jl];
            unsigned wv = ((unsigned)__builtin_bit_cast(unsigned short, hv) << 16)
                        | (unsigned)(tagbase + s + 1);
            __hip_atomic_store(ex + (((size_t)(s & 1) * 8 + g) * 16 + bb) * 512 + mem * 32 + jl,
                               wv, __ATOMIC_RELAXED, __HIP_MEMORY_SCOPE_SYSTEM);
            hs[((size_t)(t * 64 + bg * 16 + bb)) * 1024 + dir * 512 + mem * 32 + jl] = hv;
        }
    }
}

// ---------------- ctx = xsel @ out_W^T + out_b ----------------
__global__ void ctx_kernel(const _Float16* __restrict__ hs1, const float* __restrict__ outW,
                           const float* __restrict__ outb, const int* __restrict__ sel_b,
                           const int* __restrict__ sel_t, float* __restrict__ out) {
    __shared__ float As[16][68];
    __shared__ float Bs[16][68];
    __shared__ int rowbase[64];
    int tid = threadIdx.x;
    int m0 = blockIdx.x * 64, n0 = blockIdx.y * 64;
    if (tid < 64) {
        int m = m0 + tid;
        rowbase[tid] = (sel_t[m] * 64 + sel_b[m]) * 1024;
    }
    __syncthreads();
    int tx = tid & 15, ty = tid >> 4;
    float acc[4][4] = {};
    for (int k0 = 0; k0 < 1024; k0 += 16) {
        for (int e = tid; e < 1024; e += 256) {
            int ml = e >> 4, k = e & 15;
            As[k][ml] = (float)hs1[(size_t)rowbase[ml] + k0 + k];
        }
        for (int e = tid; e < 1024; e += 256) {
            int nl = e >> 4, k = e & 15;
            int n = n0 + nl;
            Bs[k][nl] = (n < EMBD) ? outW[(size_t)n * 1024 + k0 + k] : 0.f;
        }
        __syncthreads();
#pragma unroll
        for (int kk = 0; kk < 16; kk++) {
            float4 a4 = *(const float4*)&As[kk][ty * 4];
            float4 b4 = *(const float4*)&Bs[kk][tx * 4];
            float av[4] = {a4.x, a4.y, a4.z, a4.w};
            float bv[4] = {b4.x, b4.y, b4.z, b4.w};
#pragma unroll
            for (int i = 0; i < 4; i++)
#pragma unroll
                for (int jj = 0; jj < 4; jj++) acc[i][jj] += av[i] * bv[jj];
        }
        __syncthreads();
    }
    for (int i = 0; i < 4; i++) {
        int m = m0 + ty * 4 + i;
        for (int jj = 0; jj < 4; jj++) {
            int n = n0 + tx * 4 + jj;
            if (n < EMBD) out[(size_t)m * EMBD + n] = acc[i][jj] + outb[n];
        }
    }
}

// ---------------- cls = einsum('ksd,kd->ks', exp_W[eidx], xsel) + exp_b[eidx] ----------------
__global__ void cls_kernel(const _Float16* __restrict__ hs1, const float* __restrict__ expW,
                           const float* __restrict__ expb, const int* __restrict__ sel_b,
                           const int* __restrict__ sel_t, const int* __restrict__ eidx,
                           float* __restrict__ out) {
    __shared__ float xr[1024];
    int r = blockIdx.x;
    int tid = threadIdx.x;
    int e = eidx[r];
    int base = (sel_t[r] * 64 + sel_b[r]) * 1024;
    for (int qq = tid; qq < 1024; qq += 256) xr[qq] = (float)hs1[(size_t)base + qq];
    __syncthreads();
    int lane = tid & 63, wid = tid >> 6;
    for (int p = 0; p < 4; p++) {
        int s = p * 4 + wid;
        const float* wrow = expW + ((size_t)e * NSYN + s) * 1024;
        float partial = 0.f;
#pragma unroll
        for (int i = 0; i < 16; i++) {
            int k = lane + 64 * i;
            partial += xr[k] * wrow[k];
        }
        for (int off = 32; off; off >>= 1) partial += __shfl_down(partial, off);
        if (lane == 0) out[(size_t)KSEL * EMBD + (size_t)r * NSYN + s] = partial + expb[e * NSYN + s];
    }
}

extern "C" void kernel_launch(void* const* d_in, const int* in_sizes, int n_in,
                              void* d_out, int out_size, void* d_ws, size_t ws_size,
                              hipStream_t stream) {
    const int* X = (const int*)d_in[0];
    const int* Xlen = (const int*)d_in[1];
    const int* sel_b = (const int*)d_in[2];
    const int* sel_t = (const int*)d_in[3];
    const int* eidx = (const int*)d_in[4];
    const float* emb = (const float*)d_in[5];
    const float* w_ih_l0f = (const float*)d_in[6];
    const float* w_hh_l0f = (const float*)d_in[7];
    const float* b_ih_l0f = (const float*)d_in[8];
    const float* b_hh_l0f = (const float*)d_in[9];
    const float* w_ih_l0b = (const float*)d_in[10];
    const float* w_hh_l0b = (const float*)d_in[11];
    const float* b_ih_l0b = (const float*)d_in[12];
    const float* b_hh_l0b = (const float*)d_in[13];
    const float* w_ih_l1f = (const float*)d_in[14];
    const float* w_hh_l1f = (const float*)d_in[15];
    const float* b_ih_l1f = (const float*)d_in[16];
    const float* b_hh_l1f = (const float*)d_in[17];
    const float* w_ih_l1b = (const float*)d_in[18];
    const float* w_hh_l1b = (const float*)d_in[19];
    const float* b_ih_l1b = (const float*)d_in[20];
    const float* b_hh_l1b = (const float*)d_in[21];
    const float* outW = (const float*)d_in[22];
    const float* outb = (const float*)d_in[23];
    const float* expW = (const float*)d_in[24];
    const float* expb = (const float*)d_in[25];

    char* ws = (char*)d_ws;
    _Float16* gates_f = (_Float16*)ws;                        // 26,214,400 B [t][n'][b] fp16
    _Float16* gates_b = (_Float16*)(ws + 26214400);           // 26,214,400 B
    _Float16* hs0 = (_Float16*)(ws + 52428800);               // 13,107,200 B [(t*64+b)][1024]
    _Float16* hs1 = (_Float16*)(ws + 65536000);               // 13,107,200 B
    unsigned* ring = (unsigned*)(ws + 78643200);              //    524,288 B (2-slot tagged ring)
    size_t needed = 79167488;
    if (ws_size < needed) return;  // diagnostic: absmax would equal max|ref|
    float* out = (float*)d_out;

    hipFuncSetAttribute((const void*)lstm_tag_kernel,
                        hipFuncAttributeMaxDynamicSharedMemorySize, 148480);

    hipMemsetAsync(ring, 0, 524288, stream);   // clear ring tags (replay-safe)

    xproj0_kernel<<<dim3(100, 16, 2), 256, 0, stream>>>(X, emb, w_ih_l0f, w_ih_l0b,
        b_ih_l0f, b_hh_l0f, b_ih_l0b, b_hh_l0b, gates_f, gates_b);

    {
        const _Float16* a0 = gates_f; const _Float16* a1 = gates_b;
        const float* a2 = w_hh_l0f; const float* a3 = w_hh_l0b;
        const int* a4 = Xlen; _Float16* a5 = hs0; unsigned* a6 = ring; int a7 = 0;
        void* args[] = {(void*)&a0, (void*)&a1, (void*)&a2, (void*)&a3,
                        (void*)&a4, (void*)&a5, (void*)&a6, (void*)&a7};
        hipLaunchCooperativeKernel((const void*)lstm_tag_kernel, dim3(128), dim3(512), args, 148480, stream);
    }

    xproj1_kernel<<<dim3(100, 16, 2), 256, 0, stream>>>(hs0, w_ih_l1f, w_ih_l1b,
        b_ih_l1f, b_hh_l1f, b_ih_l1b, b_hh_l1b, gates_f, gates_b);

    {
        const _Float16* a0 = gates_f; const _Float16* a1 = gates_b;
        const float* a2 = w_hh_l1f; const float* a3 = w_hh_l1b;
        const int* a4 = Xlen; _Float16* a5 = hs1; unsigned* a6 = ring; int a7 = 128;
        void* args[] = {(void*)&a0, (void*)&a1, (void*)&a2, (void*)&a3,
                        (void*)&a4, (void*)&a5, (void*)&a6, (void*)&a7};
        hipLaunchCooperativeKernel((const void*)lstm_tag_kernel, dim3(128), dim3(512), args, 148480, stream);
    }

    ctx_kernel<<<dim3(32, 5), 256, 0, stream>>>(hs1, outW, outb, sel_b, sel_t, out);
    cls_kernel<<<KSEL, 256, 0, stream>>>(hs1, expW, expb, sel_b, sel_t, eidx, out);
}